// Round 8
// baseline (257.005 us; speedup 1.0000x reference)
//
#include <hip/hip_runtime.h>

// Fixed problem sizes: b=4, c=256, n=4096, cr=32.
#define Bb 4
#define Cc 256
#define Nn 4096
#define CR 32
#define EPS_BN 1e-5f
// Fixed-shift softmax: scores >= 0 (post-ReLU Q,K), bounded << 100, so
// exp(s-20) is exactly softmax-equivalent and overflow/underflow safe.
// K is pre-scaled by log2(e) in qkv, so attn uses exp2(s' - 20*log2e).
// Diagonal identity: energy_h[i,i] == energy_w[i] (both are q_i . k_i), so the
// unmasked full-row softmax PLUS v[:,i]*att[i,i] reproduces the reference's
// concat([masked energy_h, energy_w]) construction exactly.
#define SHIFT2 28.853900817779268f
#define LOG2E  1.4426950408889634f
#define TJ 64                 // j-tile
#define NTJ (Nn / TJ)         // 64 j-tiles (full row per block now)

typedef __attribute__((ext_vector_type(8))) short short8;   // 8 bf16
typedef __attribute__((ext_vector_type(4))) float f32x4;

__device__ inline unsigned int pk2(float a, float b) {
    __bf16 ha = (__bf16)a, hb = (__bf16)b;
    unsigned short ra = __builtin_bit_cast(unsigned short, ha);
    unsigned short rb = __builtin_bit_cast(unsigned short, hb);
    return ((unsigned int)rb << 16) | ra;
}
__device__ inline float ex2(float x) { return __builtin_amdgcn_exp2f(x); }

// ---------------------------------------------------------------------------
// Kernel 0 (R5): pack W (320 rows: Q32,K32,V256) into frag-major bf16 Wf.
// 160 KB total -> L2-resident for all qkv blocks.
// grid 20 blocks (one per 16-row group), 256 threads.
// ---------------------------------------------------------------------------
__global__ __launch_bounds__(256) void prep_w(
    const float* __restrict__ wq, const float* __restrict__ wk,
    const float* __restrict__ wv, __bf16* __restrict__ Wf)
{
    const int r16 = blockIdx.x;                 // 0..19
    const int tid = threadIdx.x;
#pragma unroll
    for (int ss = 0; ss < 2; ++ss) {
        int s = tid + ss * 256;                 // 0..511 = (kc 8) x (lane 64)
        int kc = s >> 6, lane = s & 63;
        int R = r16 * 16 + (lane & 15);
        const float* src = (R < 32) ? (wq + (size_t)R * Cc)
                         : (R < 64) ? (wk + (size_t)(R - 32) * Cc)
                                    : (wv + (size_t)(R - 64) * Cc);
        const float* p = src + kc * 32 + (lane >> 4) * 8;
        float4 a = *(const float4*)p;
        float4 c2 = *(const float4*)(p + 4);
        uint4 pk = { pk2(a.x,a.y), pk2(a.z,a.w), pk2(c2.x,c2.y), pk2(c2.z,c2.w) };
        *(uint4*)&Wf[(((size_t)r16 * 8 + kc) * 64 + lane) * 8] = pk;
    }
}

// ---------------------------------------------------------------------------
// Kernel 1 (R5): QKV = BN_ReLU(W x) via MFMA, split-bf16 x. Three groups:
// g0 = Q+K (4 mt), g1/g2 = V 128 rows each (8 mt). A-frags direct from
// pre-packed global Wf (L2-hot). Per-wave-private transpose, no barriers
// in the K-loop. grid (32 n-tiles, 3 groups, 4 b), block 256.
// ---------------------------------------------------------------------------
__global__ __launch_bounds__(256) void qkv_kernel(
    const float* __restrict__ x, const __bf16* __restrict__ Wf,
    const float* __restrict__ bn1s, const float* __restrict__ bn1b, const float* __restrict__ bn1m, const float* __restrict__ bn1v,
    const float* __restrict__ bn2s, const float* __restrict__ bn2b, const float* __restrict__ bn2m, const float* __restrict__ bn2v,
    const float* __restrict__ bn3s, const float* __restrict__ bn3b, const float* __restrict__ bn3m, const float* __restrict__ bn3v,
    __bf16* __restrict__ Qt, __bf16* __restrict__ Kt, __bf16* __restrict__ Vb)
{
    __shared__ __align__(16) float  sXf[4][32 * 40];       // per-wave [c][40] f32, 20.5 KB
    __shared__ __align__(16) __bf16 sXt[4][2][32 * 40];    // per-wave [plane][n][40], 20.5 KB
    __shared__ __align__(16) __bf16 oT[128 * 136];         // V epilogue transpose, 34 KB

    const int tid = threadIdx.x;
    const int n0 = blockIdx.x * 128, g = blockIdx.y, b = blockIdx.z;
    const int lane = tid & 63, w = tid >> 6;
    const int l15 = lane & 15, l4 = lane >> 4;
    const int nmt = (g == 0) ? 4 : 8;                       // row-16-groups this block
    const int r16b = (g == 0) ? 0 : 4 + (g - 1) * 8;        // base into Wf

    // per-wave LDS pointers
    float*  sXfw  = &sXf[w][0];
    __bf16* sXtw0 = &sXt[w][0][0];
    __bf16* sXtw1 = &sXt[w][1][0];

    // global loader mapping (wave-private): cr = c-row (8), nq = n-quad (8)
    const int cr = lane >> 3, nq = lane & 7;
    const float* xbase = x + (size_t)(b * Cc + cr) * Nn + n0 + w * 32 + nq * 4;

    // prefetch chunk 0
    float4 xg[4];
#pragma unroll
    for (int it = 0; it < 4; ++it)
        xg[it] = *(const float4*)&xbase[(size_t)(it * 8) * Nn];

    f32x4 acc[8][2];
#pragma unroll
    for (int mt = 0; mt < 8; ++mt)
#pragma unroll
        for (int nt = 0; nt < 2; ++nt) acc[mt][nt] = (f32x4){0.f, 0.f, 0.f, 0.f};

    for (int kc = 0; kc < 8; ++kc) {
        // stage this chunk into wave-private sXf [c][n]
#pragma unroll
        for (int it = 0; it < 4; ++it)
            *(float4*)&sXfw[(it * 8 + cr) * 40 + nq * 4] = xg[it];

        // prefetch next chunk (overlaps transpose + MFMA)
        if (kc + 1 < 8) {
#pragma unroll
            for (int it = 0; it < 4; ++it)
                xg[it] = *(const float4*)&xbase[(size_t)((kc + 1) * 32 + it * 8) * Nn];
        }

        // wave-private transpose + hi/lo split: 2 slots of (n, 8 c) per lane
#pragma unroll
        for (int s = 0; s < 2; ++s) {
            int n = lane & 31, c0 = (lane >> 5) * 8 + s * 16;
            float h[8], lo[8];
#pragma unroll
            for (int j = 0; j < 8; ++j) {
                float v = sXfw[(c0 + j) * 40 + n];
                float hh = (float)(__bf16)v;
                h[j] = hh; lo[j] = v - hh;
            }
            uint4 H = { pk2(h[0],h[1]), pk2(h[2],h[3]), pk2(h[4],h[5]), pk2(h[6],h[7]) };
            uint4 L = { pk2(lo[0],lo[1]), pk2(lo[2],lo[3]), pk2(lo[4],lo[5]), pk2(lo[6],lo[7]) };
            *(uint4*)&sXtw0[n * 40 + c0] = H;
            *(uint4*)&sXtw1[n * 40 + c0] = L;
        }

        // B-frags (wave-private rows), A-frags from global Wf, MFMA
        short8 bh[2], bl[2];
#pragma unroll
        for (int nt = 0; nt < 2; ++nt) {
            bh[nt] = *(const short8*)&sXtw0[(nt * 16 + l15) * 40 + l4 * 8];
            bl[nt] = *(const short8*)&sXtw1[(nt * 16 + l15) * 40 + l4 * 8];
        }
        short8 af[8];
#pragma unroll
        for (int mt = 0; mt < 8; ++mt)
            if (mt < nmt)
                af[mt] = *(const short8*)&Wf[(((size_t)(r16b + mt) * 8 + kc) * 64 + lane) * 8];
#pragma unroll
        for (int mt = 0; mt < 8; ++mt) {
            if (mt < nmt) {
#pragma unroll
                for (int nt = 0; nt < 2; ++nt) {
                    acc[mt][nt] = __builtin_amdgcn_mfma_f32_16x16x32_bf16(af[mt], bh[nt], acc[mt][nt], 0, 0, 0);
                    acc[mt][nt] = __builtin_amdgcn_mfma_f32_16x16x32_bf16(af[mt], bl[nt], acc[mt][nt], 0, 0, 0);
                }
            }
        }
    }

    // ---- epilogue: BN fold + ReLU + store ----
    if (g == 0) {
        // Q (mt<2) / K (mt>=2, log2e-scaled): [n][d] uint2 stores
#pragma unroll
        for (int mt = 0; mt < 4; ++mt) {
            float scl[4], off[4];
#pragma unroll
            for (int r = 0; r < 4; ++r) {
                int R = mt * 16 + l4 * 4 + r;
                float s, o;
                if (R < 32) {
                    s = bn1s[R] * __frsqrt_rn(bn1v[R] + EPS_BN);
                    o = bn1b[R] - bn1m[R] * s;
                } else {
                    int row = R - 32;
                    s = bn2s[row] * __frsqrt_rn(bn2v[row] + EPS_BN);
                    o = bn2b[row] - bn2m[row] * s;
                    s *= LOG2E; o *= LOG2E;
                }
                scl[r] = s; off[r] = o;
            }
            __bf16* dst = (mt < 2) ? Qt : Kt;
            int d0 = (mt & 1) * 16 + l4 * 4;
#pragma unroll
            for (int nt = 0; nt < 2; ++nt) {
                f32x4 a = acc[mt][nt];
                float e0 = fmaxf(fmaf(a.x, scl[0], off[0]), 0.f);
                float e1 = fmaxf(fmaf(a.y, scl[1], off[1]), 0.f);
                float e2 = fmaxf(fmaf(a.z, scl[2], off[2]), 0.f);
                float e3 = fmaxf(fmaf(a.w, scl[3], off[3]), 0.f);
                uint2 p = { pk2(e0, e1), pk2(e2, e3) };
                int n = n0 + w * 32 + nt * 16 + l15;
                *(uint2*)&dst[(size_t)(b * Nn + n) * CR + d0] = p;
            }
        }
    } else {
        // V (128 rows): transpose via oT, coalesced [c][n] stores
        const int vr0 = (g - 1) * 128;
#pragma unroll
        for (int mt = 0; mt < 8; ++mt) {
            float scl[4], off[4];
#pragma unroll
            for (int r = 0; r < 4; ++r) {
                int row = vr0 + mt * 16 + l4 * 4 + r;
                float s = bn3s[row] * __frsqrt_rn(bn3v[row] + EPS_BN);
                scl[r] = s; off[r] = bn3b[row] - bn3m[row] * s;
            }
#pragma unroll
            for (int nt = 0; nt < 2; ++nt) {
                f32x4 a = acc[mt][nt];
                float e[4];
                e[0] = fmaxf(fmaf(a.x, scl[0], off[0]), 0.f);
                e[1] = fmaxf(fmaf(a.y, scl[1], off[1]), 0.f);
                e[2] = fmaxf(fmaf(a.z, scl[2], off[2]), 0.f);
                e[3] = fmaxf(fmaf(a.w, scl[3], off[3]), 0.f);
                int ncol = w * 32 + nt * 16 + l15;
#pragma unroll
                for (int r = 0; r < 4; ++r)
                    oT[(mt * 16 + l4 * 4 + r) * 136 + ncol] = (__bf16)e[r];
            }
        }
        __syncthreads();
        int rr = tid >> 1, qq = tid & 1;          // 128 rows x 2 n-halves
        size_t vrow = (size_t)(b * Cc + vr0 + rr) * Nn + n0 + qq * 64;
#pragma unroll
        for (int e8 = 0; e8 < 8; ++e8)
            *(uint4*)&Vb[vrow + e8 * 8] = *(const uint4*)&oT[rr * 136 + qq * 64 + e8 * 8];
    }
}

// ---------------------------------------------------------------------------
// Kernel 2 (R8): FUSED attention. JSPLIT=1 -- each block owns i-tile 32 x
// full j=4096, so the softmax denominator completes in-block and the kernel
// writes out = gamma*(O/l) + x DIRECTLY. Deletes reduce_kernel + the 67 MB
// PO/PL HBM round-trip (the largest non-attn cost, ~30-35 us).
// Skeleton = the proven R0 two-barrier tile loop (R6/R7: all schedule
// variants within noise). Wave roles per tile: QK j-slice [16w,16w+16)
// (it<2 now), PV c-slice [64w,64w+64).
// Epilogue: cross-wave l reduce -> sLinv; per-lane normalize (C-layout rows
// i = it*16+l4*4+r matches sLinv float4); transpose via oT[256][36] f32;
// coalesced gamma*o+x write. Aggregate MFMA work identical to JSPLIT=4
// (same (i,j) pairs, 512 blocks x 2x work). ~150 regs -> 8 waves/CU, same
// as the 77 us baseline; plain launch_bounds (R3 lesson: never pin).
// grid (128 i-tiles, 4 b) = 512 blocks, block 256 (4 waves).
// ---------------------------------------------------------------------------
__global__ __launch_bounds__(256) void attn_kernel(
    const __bf16* __restrict__ Qt, const __bf16* __restrict__ Kt,
    const __bf16* __restrict__ Vb,
    const float* __restrict__ x, const float* __restrict__ gamma,
    float* __restrict__ out)
{
    __shared__ __align__(16) __bf16 sQ[32 * 40];    // 2.5 KB
    __shared__ __align__(16) __bf16 sP[32 * 72];    // 4.6 KB
    __shared__ __align__(16) float  sL[4][32];      // 0.5 KB
    __shared__ __align__(16) float  sLinv[32];      // 128 B
    __shared__ __align__(16) float  oT[256 * 36];   // 36.9 KB  [c][i], pitch 36 (16B-aligned rows)

    const int tid = threadIdx.x, lane = tid & 63, w = tid >> 6;
    const int b = blockIdx.y, iblk = blockIdx.x;
    const int i0 = iblk * 32;
    const int l15 = lane & 15, l4 = lane >> 4;

    // stage Q tile [i][d] (32 rows), then per-wave B-frags (held all kernel)
    if (tid < 128) {
        int i = tid >> 2, o = tid & 3;
        *(uint4*)&sQ[i * 40 + o * 8] =
            *(const uint4*)&Qt[(size_t)(b * Nn + i0 + i) * CR + o * 8];
    }
    __syncthreads();
    short8 qf[2];
#pragma unroll
    for (int it = 0; it < 2; ++it)
        qf[it] = *(const short8*)&sQ[(it * 16 + l15) * 40 + l4 * 8];

    f32x4 oacc[8];
#pragma unroll
    for (int z = 0; z < 8; ++z) oacc[z] = (f32x4){0.f, 0.f, 0.f, 0.f};
    float lp[2] = {0.f, 0.f};

    short8 kf = *(const short8*)&Kt[(size_t)(b * Nn + 16 * w + l15) * CR + l4 * 8];

    for (int t = 0; t < NTJ; ++t) {
        const size_t j0 = (size_t)t * TJ;

        // issue this tile's V B-frag loads (consumed after barrier A)
        short8 vf[8];
#pragma unroll
        for (int u = 0; u < 8; ++u) {
            int jh = u >> 2, ct = u & 3;
            int c = w * 64 + ct * 16 + l15;
            vf[u] = *(const short8*)&Vb[(size_t)(b * Cc + c) * Nn + j0 + (jh * 4 + l4) * 8];
        }

        // scores: wave w owns j-slice [16w,16w+16): S^T = K.Q^T, exp2 -> sP
#pragma unroll
        for (int it = 0; it < 2; ++it) {
            f32x4 c0 = (f32x4){0.f, 0.f, 0.f, 0.f};
            c0 = __builtin_amdgcn_mfma_f32_16x16x32_bf16(kf, qf[it], c0, 0, 0, 0);
            float e0 = ex2(c0.x - SHIFT2);
            float e1 = ex2(c0.y - SHIFT2);
            float e2 = ex2(c0.z - SHIFT2);
            float e3 = ex2(c0.w - SHIFT2);
            lp[it] += (e0 + e1) + (e2 + e3);
            uint2 p2 = { pk2(e0, e1), pk2(e2, e3) };
            *(uint2*)&sP[(it * 16 + l15) * 72 + w * 16 + l4 * 4] = p2;
        }
        __syncthreads();   // barrier A: sP visible to all waves

        // prefetch next tile's K A-frag during PV
        if (t + 1 < NTJ)
            kf = *(const short8*)&Kt[(size_t)(b * Nn + j0 + TJ + 16 * w + l15) * CR + l4 * 8];

        // PV: wave w owns c-slice [64w,64w+64)
        __builtin_amdgcn_s_setprio(1);
#pragma unroll
        for (int jh = 0; jh < 2; ++jh) {
            short8 pf[2];
#pragma unroll
            for (int it = 0; it < 2; ++it)
                pf[it] = *(const short8*)&sP[(it * 16 + l15) * 72 + jh * 32 + l4 * 8];
#pragma unroll
            for (int ct = 0; ct < 4; ++ct) {
#pragma unroll
                for (int it = 0; it < 2; ++it)
                    oacc[it * 4 + ct] = __builtin_amdgcn_mfma_f32_16x16x32_bf16(
                        pf[it], vf[jh * 4 + ct], oacc[it * 4 + ct], 0, 0, 0);
            }
        }
        __builtin_amdgcn_s_setprio(0);
        __syncthreads();   // barrier B: protect sP for next tile
    }

    // ---- fused softmax-denominator + epilogue ----
    // full row sums l (j complete in-block): wave partial -> sL -> sLinv
#pragma unroll
    for (int it = 0; it < 2; ++it) {
        float v = lp[it];
        v += __shfl_xor(v, 16);
        v += __shfl_xor(v, 32);
        if (lane < 16) sL[w][it * 16 + lane] = v;
    }
    __syncthreads();
    if (tid < 32)
        sLinv[tid] = 1.0f / (sL[0][tid] + sL[1][tid] + sL[2][tid] + sL[3][tid]);
    __syncthreads();

    // normalize (per-i linv: oacc elem r <-> i = it*16 + l4*4 + r) and
    // transpose into oT[c][i] (pitch 36: 16B-aligned rows, ~2-way banks)
#pragma unroll
    for (int it = 0; it < 2; ++it) {
        float4 li = *(const float4*)&sLinv[it * 16 + l4 * 4];
#pragma unroll
        for (int ct = 0; ct < 4; ++ct) {
            f32x4 a = oacc[it * 4 + ct];
            int c = w * 64 + ct * 16 + l15;
            float4 tv = { a.x * li.x, a.y * li.y, a.z * li.z, a.w * li.w };
            *(float4*)&oT[c * 36 + it * 16 + l4 * 4] = tv;
        }
    }
    __syncthreads();

    // out = gamma * o + x : 256 c x 32 i, 2 threads per c row (16 i each)
    const float g = gamma[0];
#pragma unroll
    for (int rep = 0; rep < 2; ++rep) {
        int c_l = (tid >> 1) + rep * 128, icol = (tid & 1) * 16;
        size_t gb = (size_t)(b * Cc + c_l) * Nn + i0 + icol;
#pragma unroll
        for (int k4 = 0; k4 < 4; ++k4) {
            float4 ov = *(const float4*)&oT[c_l * 36 + icol + k4 * 4];
            float4 xv = *(const float4*)&x[gb + k4 * 4];
            float4 res;
            res.x = fmaf(g, ov.x, xv.x);
            res.y = fmaf(g, ov.y, xv.y);
            res.z = fmaf(g, ov.z, xv.z);
            res.w = fmaf(g, ov.w, xv.w);
            *(float4*)&out[gb + k4 * 4] = res;
        }
    }
}

// ---------------------------------------------------------------------------
extern "C" void kernel_launch(void* const* d_in, const int* in_sizes, int n_in,
                              void* d_out, int out_size, void* d_ws, size_t ws_size,
                              hipStream_t stream)
{
    const float* x    = (const float*)d_in[0];
    const float* wq   = (const float*)d_in[1];
    const float* wk   = (const float*)d_in[2];
    const float* wv   = (const float*)d_in[3];
    const float* bn1s = (const float*)d_in[4];
    const float* bn1b = (const float*)d_in[5];
    const float* bn1m = (const float*)d_in[6];
    const float* bn1v = (const float*)d_in[7];
    const float* bn2s = (const float*)d_in[8];
    const float* bn2b = (const float*)d_in[9];
    const float* bn2m = (const float*)d_in[10];
    const float* bn2v = (const float*)d_in[11];
    const float* bn3s = (const float*)d_in[12];
    const float* bn3b = (const float*)d_in[13];
    const float* bn3m = (const float*)d_in[14];
    const float* bn3v = (const float*)d_in[15];
    const float* gmm  = (const float*)d_in[16];
    float* out = (float*)d_out;

    // workspace layout (bytes): [Qt 1M][Kt 1M][Vb 8M][Wf 160K @ +10M]
    char* ws = (char*)d_ws;
    __bf16* Qt  = (__bf16*)(ws);
    __bf16* Kt  = (__bf16*)(ws + (1u << 20));
    __bf16* Vb  = (__bf16*)(ws + (2u << 20));
    __bf16* Wf  = (__bf16*)(ws + (10u << 20));

    prep_w<<<dim3(20), 256, 0, stream>>>(wq, wk, wv, Wf);

    qkv_kernel<<<dim3(Nn / 128, 3, Bb), 256, 0, stream>>>(
        x, Wf,
        bn1s, bn1b, bn1m, bn1v,
        bn2s, bn2b, bn2m, bn2v,
        bn3s, bn3b, bn3m, bn3v,
        Qt, Kt, Vb);

    attn_kernel<<<dim3(Nn / 32, Bb), 256, 0, stream>>>(Qt, Kt, Vb, x, gmm, out);
}

// Round 9
// 202.606 us; speedup vs baseline: 1.2685x; 1.2685x over previous
//
#include <hip/hip_runtime.h>

// Fixed problem sizes: b=4, c=256, n=4096, cr=32.
#define Bb 4
#define Cc 256
#define Nn 4096
#define CR 32
#define EPS_BN 1e-5f
// Fixed-shift softmax: scores >= 0 (post-ReLU Q,K), bounded << 100, so
// exp(s-20) is exactly softmax-equivalent and overflow/underflow safe.
// K is pre-scaled by log2(e) in qkv, so attn uses exp2(s' - 20*log2e).
#define SHIFT2 28.853900817779268f
#define LOG2E  1.4426950408889634f
#define JSPLIT 2
#define JSL (Nn / JSPLIT)    // 2048 j per attention block
#define TJ 128               // j-tile (doubled; 8 waves cover 8 x 16 j)
#define NTILES (JSL / TJ)    // 16

typedef __attribute__((ext_vector_type(8))) short short8;   // 8 bf16
typedef __attribute__((ext_vector_type(4))) float f32x4;

__device__ inline unsigned int pk2(float a, float b) {
    __bf16 ha = (__bf16)a, hb = (__bf16)b;
    unsigned short ra = __builtin_bit_cast(unsigned short, ha);
    unsigned short rb = __builtin_bit_cast(unsigned short, hb);
    return ((unsigned int)rb << 16) | ra;
}
__device__ inline float blo(unsigned int u) { return __uint_as_float(u << 16); }
__device__ inline float bhi(unsigned int u) { return __uint_as_float(u & 0xffff0000u); }
__device__ inline float ex2(float x) { return __builtin_amdgcn_exp2f(x); }

// ---------------------------------------------------------------------------
// Kernel 0 (R5): pack W (320 rows: Q32,K32,V256) into frag-major bf16 Wf.
// 160 KB total -> L2-resident for all qkv blocks.
// grid 20 blocks (one per 16-row group), 256 threads.
// ---------------------------------------------------------------------------
__global__ __launch_bounds__(256) void prep_w(
    const float* __restrict__ wq, const float* __restrict__ wk,
    const float* __restrict__ wv, __bf16* __restrict__ Wf)
{
    const int r16 = blockIdx.x;                 // 0..19
    const int tid = threadIdx.x;
#pragma unroll
    for (int ss = 0; ss < 2; ++ss) {
        int s = tid + ss * 256;                 // 0..511 = (kc 8) x (lane 64)
        int kc = s >> 6, lane = s & 63;
        int R = r16 * 16 + (lane & 15);
        const float* src = (R < 32) ? (wq + (size_t)R * Cc)
                         : (R < 64) ? (wk + (size_t)(R - 32) * Cc)
                                    : (wv + (size_t)(R - 64) * Cc);
        const float* p = src + kc * 32 + (lane >> 4) * 8;
        float4 a = *(const float4*)p;
        float4 c2 = *(const float4*)(p + 4);
        uint4 pk = { pk2(a.x,a.y), pk2(a.z,a.w), pk2(c2.x,c2.y), pk2(c2.z,c2.w) };
        *(uint4*)&Wf[(((size_t)r16 * 8 + kc) * 64 + lane) * 8] = pk;
    }
}

// ---------------------------------------------------------------------------
// Kernel 1 (R5): QKV = BN_ReLU(W x) via MFMA, split-bf16 x. Three groups:
// g0 = Q+K (4 mt), g1/g2 = V 128 rows each (8 mt). A-frags direct from
// pre-packed global Wf (L2-hot). Per-wave-private transpose, no barriers
// in the K-loop. grid (32 n-tiles, 3 groups, 4 b), block 256.
// ---------------------------------------------------------------------------
__global__ __launch_bounds__(256) void qkv_kernel(
    const float* __restrict__ x, const __bf16* __restrict__ Wf,
    const float* __restrict__ bn1s, const float* __restrict__ bn1b, const float* __restrict__ bn1m, const float* __restrict__ bn1v,
    const float* __restrict__ bn2s, const float* __restrict__ bn2b, const float* __restrict__ bn2m, const float* __restrict__ bn2v,
    const float* __restrict__ bn3s, const float* __restrict__ bn3b, const float* __restrict__ bn3m, const float* __restrict__ bn3v,
    __bf16* __restrict__ Qt, __bf16* __restrict__ Kt, __bf16* __restrict__ Vb)
{
    __shared__ __align__(16) float  sXf[4][32 * 40];       // per-wave [c][40] f32, 20.5 KB
    __shared__ __align__(16) __bf16 sXt[4][2][32 * 40];    // per-wave [plane][n][40], 20.5 KB
    __shared__ __align__(16) __bf16 oT[128 * 136];         // V epilogue transpose, 34 KB

    const int tid = threadIdx.x;
    const int n0 = blockIdx.x * 128, g = blockIdx.y, b = blockIdx.z;
    const int lane = tid & 63, w = tid >> 6;
    const int l15 = lane & 15, l4 = lane >> 4;
    const int nmt = (g == 0) ? 4 : 8;                       // row-16-groups this block
    const int r16b = (g == 0) ? 0 : 4 + (g - 1) * 8;        // base into Wf

    // per-wave LDS pointers
    float*  sXfw  = &sXf[w][0];
    __bf16* sXtw0 = &sXt[w][0][0];
    __bf16* sXtw1 = &sXt[w][1][0];

    // global loader mapping (wave-private): cr = c-row (8), nq = n-quad (8)
    const int cr = lane >> 3, nq = lane & 7;
    const float* xbase = x + (size_t)(b * Cc + cr) * Nn + n0 + w * 32 + nq * 4;

    // prefetch chunk 0
    float4 xg[4];
#pragma unroll
    for (int it = 0; it < 4; ++it)
        xg[it] = *(const float4*)&xbase[(size_t)(it * 8) * Nn];

    f32x4 acc[8][2];
#pragma unroll
    for (int mt = 0; mt < 8; ++mt)
#pragma unroll
        for (int nt = 0; nt < 2; ++nt) acc[mt][nt] = (f32x4){0.f, 0.f, 0.f, 0.f};

    for (int kc = 0; kc < 8; ++kc) {
        // stage this chunk into wave-private sXf [c][n]
#pragma unroll
        for (int it = 0; it < 4; ++it)
            *(float4*)&sXfw[(it * 8 + cr) * 40 + nq * 4] = xg[it];

        // prefetch next chunk (overlaps transpose + MFMA)
        if (kc + 1 < 8) {
#pragma unroll
            for (int it = 0; it < 4; ++it)
                xg[it] = *(const float4*)&xbase[(size_t)((kc + 1) * 32 + it * 8) * Nn];
        }

        // wave-private transpose + hi/lo split: 2 slots of (n, 8 c) per lane
#pragma unroll
        for (int s = 0; s < 2; ++s) {
            int n = lane & 31, c0 = (lane >> 5) * 8 + s * 16;
            float h[8], lo[8];
#pragma unroll
            for (int j = 0; j < 8; ++j) {
                float v = sXfw[(c0 + j) * 40 + n];
                float hh = (float)(__bf16)v;
                h[j] = hh; lo[j] = v - hh;
            }
            uint4 H = { pk2(h[0],h[1]), pk2(h[2],h[3]), pk2(h[4],h[5]), pk2(h[6],h[7]) };
            uint4 L = { pk2(lo[0],lo[1]), pk2(lo[2],lo[3]), pk2(lo[4],lo[5]), pk2(lo[6],lo[7]) };
            *(uint4*)&sXtw0[n * 40 + c0] = H;
            *(uint4*)&sXtw1[n * 40 + c0] = L;
        }

        // B-frags (wave-private rows), A-frags from global Wf, MFMA
        short8 bh[2], bl[2];
#pragma unroll
        for (int nt = 0; nt < 2; ++nt) {
            bh[nt] = *(const short8*)&sXtw0[(nt * 16 + l15) * 40 + l4 * 8];
            bl[nt] = *(const short8*)&sXtw1[(nt * 16 + l15) * 40 + l4 * 8];
        }
        short8 af[8];
#pragma unroll
        for (int mt = 0; mt < 8; ++mt)
            if (mt < nmt)
                af[mt] = *(const short8*)&Wf[(((size_t)(r16b + mt) * 8 + kc) * 64 + lane) * 8];
#pragma unroll
        for (int mt = 0; mt < 8; ++mt) {
            if (mt < nmt) {
#pragma unroll
                for (int nt = 0; nt < 2; ++nt) {
                    acc[mt][nt] = __builtin_amdgcn_mfma_f32_16x16x32_bf16(af[mt], bh[nt], acc[mt][nt], 0, 0, 0);
                    acc[mt][nt] = __builtin_amdgcn_mfma_f32_16x16x32_bf16(af[mt], bl[nt], acc[mt][nt], 0, 0, 0);
                }
            }
        }
    }

    // ---- epilogue: BN fold + ReLU + store ----
    if (g == 0) {
        // Q (mt<2) / K (mt>=2, log2e-scaled): [n][d] uint2 stores
#pragma unroll
        for (int mt = 0; mt < 4; ++mt) {
            float scl[4], off[4];
#pragma unroll
            for (int r = 0; r < 4; ++r) {
                int R = mt * 16 + l4 * 4 + r;
                float s, o;
                if (R < 32) {
                    s = bn1s[R] * __frsqrt_rn(bn1v[R] + EPS_BN);
                    o = bn1b[R] - bn1m[R] * s;
                } else {
                    int row = R - 32;
                    s = bn2s[row] * __frsqrt_rn(bn2v[row] + EPS_BN);
                    o = bn2b[row] - bn2m[row] * s;
                    s *= LOG2E; o *= LOG2E;
                }
                scl[r] = s; off[r] = o;
            }
            __bf16* dst = (mt < 2) ? Qt : Kt;
            int d0 = (mt & 1) * 16 + l4 * 4;
#pragma unroll
            for (int nt = 0; nt < 2; ++nt) {
                f32x4 a = acc[mt][nt];
                float e0 = fmaxf(fmaf(a.x, scl[0], off[0]), 0.f);
                float e1 = fmaxf(fmaf(a.y, scl[1], off[1]), 0.f);
                float e2 = fmaxf(fmaf(a.z, scl[2], off[2]), 0.f);
                float e3 = fmaxf(fmaf(a.w, scl[3], off[3]), 0.f);
                uint2 p = { pk2(e0, e1), pk2(e2, e3) };
                int n = n0 + w * 32 + nt * 16 + l15;
                *(uint2*)&dst[(size_t)(b * Nn + n) * CR + d0] = p;
            }
        }
    } else {
        // V (128 rows): transpose via oT, coalesced [c][n] stores
        const int vr0 = (g - 1) * 128;
#pragma unroll
        for (int mt = 0; mt < 8; ++mt) {
            float scl[4], off[4];
#pragma unroll
            for (int r = 0; r < 4; ++r) {
                int row = vr0 + mt * 16 + l4 * 4 + r;
                float s = bn3s[row] * __frsqrt_rn(bn3v[row] + EPS_BN);
                scl[r] = s; off[r] = bn3b[row] - bn3m[row] * s;
            }
#pragma unroll
            for (int nt = 0; nt < 2; ++nt) {
                f32x4 a = acc[mt][nt];
                float e[4];
                e[0] = fmaxf(fmaf(a.x, scl[0], off[0]), 0.f);
                e[1] = fmaxf(fmaf(a.y, scl[1], off[1]), 0.f);
                e[2] = fmaxf(fmaf(a.z, scl[2], off[2]), 0.f);
                e[3] = fmaxf(fmaf(a.w, scl[3], off[3]), 0.f);
                int ncol = w * 32 + nt * 16 + l15;
#pragma unroll
                for (int r = 0; r < 4; ++r)
                    oT[(mt * 16 + l4 * 4 + r) * 136 + ncol] = (__bf16)e[r];
            }
        }
        __syncthreads();
        int rr = tid >> 1, qq = tid & 1;          // 128 rows x 2 n-halves
        size_t vrow = (size_t)(b * Cc + vr0 + rr) * Nn + n0 + qq * 64;
#pragma unroll
        for (int e8 = 0; e8 < 8; ++e8)
            *(uint4*)&Vb[vrow + e8 * 8] = *(const uint4*)&oT[rr * 136 + qq * 64 + e8 * 8];
    }
}

// ---------------------------------------------------------------------------
// Kernel 2 (R9): tile-iteration halving. Empirical law from R0-R8:
// attn_time = rounds x tiles_per_block x ~2.4us (per-tile latency invariant
// across all schedule/occupancy variants). R0: 2x16 = 78us; R8: 1x64 = 142us.
// R9 targets 1x16: 8-wave (512-thr) blocks, TJ=128, JSPLIT=2 -> grid 512
// blocks; per-wave oacc halves to 8xf32x4 (32 regs) and qf is re-read from
// LDS per tile, so the live set fits ~4 waves/SIMD -> 2 blocks/CU -> all 512
// resident = ONE round. Per-wave per-tile work is IDENTICAL to R0 (1 kf,
// 4 QK MFMA, 16 exp2, 32 PV MFMA, 8 vf in 2-deep jh rotation).
// No launch_bounds pin (R3 lesson). Proven 2-barrier skeleton + setprio.
// grid (64 i-tiles, 2 js, 4 b) = 512 blocks, block 512 (8 waves).
// ---------------------------------------------------------------------------
__global__ __launch_bounds__(512) void attn_kernel(
    const __bf16* __restrict__ Qt, const __bf16* __restrict__ Kt,
    const __bf16* __restrict__ Vb,
    __bf16* __restrict__ PO, float* __restrict__ PL)
{
    __shared__ __align__(16) __bf16 sQ[64 * 40];    // 5.1 KB
    __shared__ __align__(16) __bf16 sP[64 * 136];   // 17.4 KB (128 j + 8 pad)
    __shared__ __align__(16) float  sL[8][64];      // 2 KB

    const int tid = threadIdx.x, lane = tid & 63, w = tid >> 6;   // w 0..7
    const int b = blockIdx.z, js = blockIdx.y, iblk = blockIdx.x;
    const int i0 = iblk * 64;
    const int l15 = lane & 15, l4 = lane >> 4;

    // stage Q tile [i][d] once (re-read per tile from LDS to save registers)
    if (tid < 256) {
        int i = tid >> 2, o = tid & 3;
        *(uint4*)&sQ[i * 40 + o * 8] =
            *(const uint4*)&Qt[(size_t)(b * Nn + i0 + i) * CR + o * 8];
    }
    __syncthreads();

    f32x4 oacc[8];
#pragma unroll
    for (int z = 0; z < 8; ++z) oacc[z] = (f32x4){0.f, 0.f, 0.f, 0.f};
    float lp[4] = {0.f, 0.f, 0.f, 0.f};

    const size_t jb = (size_t)js * JSL;
    // QK: wave w owns j-slice [16w, 16w+16) of each 128-j tile
    short8 kf = *(const short8*)&Kt[(size_t)(b * Nn + jb + 16 * w + l15) * CR + l4 * 8];
    // PV: wave w owns c-slice [32w, 32w+32); ct adds 16 rows
    const __bf16* vrow0 = Vb + (size_t)(b * Cc + w * 32 + l15) * Nn;

    for (int t = 0; t < NTILES; ++t) {
        const size_t j0 = jb + (size_t)t * TJ;

        // vf double-buffer: issue jh0/jh1 loads now (cover under QK+softmax)
        short8 v0[2], v1[2];
#pragma unroll
        for (int ct = 0; ct < 2; ++ct)
            v0[ct] = *(const short8*)&vrow0[(size_t)(ct * 16) * Nn + j0 + l4 * 8];
#pragma unroll
        for (int ct = 0; ct < 2; ++ct)
            v1[ct] = *(const short8*)&vrow0[(size_t)(ct * 16) * Nn + j0 + 32 + l4 * 8];

        // qf from LDS (transient -> low register pressure)
        short8 qf[4];
#pragma unroll
        for (int it = 0; it < 4; ++it)
            qf[it] = *(const short8*)&sQ[(it * 16 + l15) * 40 + l4 * 8];

        // scores: S^T = K.Q^T over this wave's 16 j, exp2, pack -> sP
#pragma unroll
        for (int it = 0; it < 4; ++it) {
            f32x4 c0 = (f32x4){0.f, 0.f, 0.f, 0.f};
            c0 = __builtin_amdgcn_mfma_f32_16x16x32_bf16(kf, qf[it], c0, 0, 0, 0);
            float e0 = ex2(c0.x - SHIFT2);
            float e1 = ex2(c0.y - SHIFT2);
            float e2 = ex2(c0.z - SHIFT2);
            float e3 = ex2(c0.w - SHIFT2);
            lp[it] += (e0 + e1) + (e2 + e3);
            uint2 p2 = { pk2(e0, e1), pk2(e2, e3) };
            *(uint2*)&sP[(it * 16 + l15) * 136 + w * 16 + l4 * 4] = p2;
        }
        __syncthreads();   // barrier A: sP visible to all waves

        // prefetch next tile's K A-frag during PV
        if (t + 1 < NTILES)
            kf = *(const short8*)&Kt[(size_t)(b * Nn + j0 + TJ + 16 * w + l15) * CR + l4 * 8];

        __builtin_amdgcn_s_setprio(1);
        // jh = 0 (v0), then refill v0 <- jh2
        {
            short8 pf[4];
#pragma unroll
            for (int it = 0; it < 4; ++it)
                pf[it] = *(const short8*)&sP[(it * 16 + l15) * 136 + l4 * 8];
#pragma unroll
            for (int ct = 0; ct < 2; ++ct)
#pragma unroll
                for (int it = 0; it < 4; ++it)
                    oacc[it * 2 + ct] = __builtin_amdgcn_mfma_f32_16x16x32_bf16(
                        pf[it], v0[ct], oacc[it * 2 + ct], 0, 0, 0);
        }
#pragma unroll
        for (int ct = 0; ct < 2; ++ct)
            v0[ct] = *(const short8*)&vrow0[(size_t)(ct * 16) * Nn + j0 + 64 + l4 * 8];
        // jh = 1 (v1), then refill v1 <- jh3
        {
            short8 pf[4];
#pragma unroll
            for (int it = 0; it < 4; ++it)
                pf[it] = *(const short8*)&sP[(it * 16 + l15) * 136 + 32 + l4 * 8];
#pragma unroll
            for (int ct = 0; ct < 2; ++ct)
#pragma unroll
                for (int it = 0; it < 4; ++it)
                    oacc[it * 2 + ct] = __builtin_amdgcn_mfma_f32_16x16x32_bf16(
                        pf[it], v1[ct], oacc[it * 2 + ct], 0, 0, 0);
        }
#pragma unroll
        for (int ct = 0; ct < 2; ++ct)
            v1[ct] = *(const short8*)&vrow0[(size_t)(ct * 16) * Nn + j0 + 96 + l4 * 8];
        // jh = 2 (v0)
        {
            short8 pf[4];
#pragma unroll
            for (int it = 0; it < 4; ++it)
                pf[it] = *(const short8*)&sP[(it * 16 + l15) * 136 + 64 + l4 * 8];
#pragma unroll
            for (int ct = 0; ct < 2; ++ct)
#pragma unroll
                for (int it = 0; it < 4; ++it)
                    oacc[it * 2 + ct] = __builtin_amdgcn_mfma_f32_16x16x32_bf16(
                        pf[it], v0[ct], oacc[it * 2 + ct], 0, 0, 0);
        }
        // jh = 3 (v1)
        {
            short8 pf[4];
#pragma unroll
            for (int it = 0; it < 4; ++it)
                pf[it] = *(const short8*)&sP[(it * 16 + l15) * 136 + 96 + l4 * 8];
#pragma unroll
            for (int ct = 0; ct < 2; ++ct)
#pragma unroll
                for (int it = 0; it < 4; ++it)
                    oacc[it * 2 + ct] = __builtin_amdgcn_mfma_f32_16x16x32_bf16(
                        pf[it], v1[ct], oacc[it * 2 + ct], 0, 0, 0);
        }
        __builtin_amdgcn_s_setprio(0);
        __syncthreads();   // barrier B: protect sP for next tile
    }

    // partial row sums l -> PL (each wave summed its own j-slices; 8-way add)
#pragma unroll
    for (int it = 0; it < 4; ++it) {
        float v = lp[it];
        v += __shfl_xor(v, 16);
        v += __shfl_xor(v, 32);
        if (lane < 16) sL[w][it * 16 + lane] = v;
    }
    __syncthreads();
    if (tid < 64) {
        float s = 0.f;
#pragma unroll
        for (int w8 = 0; w8 < 8; ++w8) s += sL[w8][tid];
        PL[(size_t)(js * Bb + b) * Nn + i0 + tid] = s;
    }

    // store partials in raw C-layout, bf16-packed (4 consecutive i per uint2).
    // c-16-group g16 = w*2 + ct; slot s = (g16>>2)*16 + it*4 + (g16&3)
    // reproduces the original layout -> reduce_kernel unchanged.
    const size_t base = (size_t)((js * Bb + b) * (Nn / 64) + iblk) * 16384;
#pragma unroll
    for (int it = 0; it < 4; ++it)
#pragma unroll
        for (int ct = 0; ct < 2; ++ct) {
            f32x4 a = oacc[it * 2 + ct];
            uint2 p = { pk2(a.x, a.y), pk2(a.z, a.w) };
            int g16 = w * 2 + ct;
            int s = (g16 >> 2) * 16 + it * 4 + (g16 & 3);
            *(uint2*)&PO[base + (size_t)(s * 64 + lane) * 4] = p;
        }
}

// ---------------------------------------------------------------------------
// Kernel 3: sum JSPLIT j-split partials, normalize, transpose via LDS,
// out = gamma * o + x. grid (64 i-tiles, 4 c-quarters, 4 b), block 256.
// ---------------------------------------------------------------------------
__global__ __launch_bounds__(256) void reduce_kernel(
    const __bf16* __restrict__ PO, const float* __restrict__ PL,
    const float* __restrict__ x, const float* __restrict__ gamma,
    float* __restrict__ out)
{
    __shared__ __align__(16) float oT[64 * 68];   // 17.4 KB
    __shared__ float sLinv[64];

    const int tid = threadIdx.x;
    const int iblk = blockIdx.x, wq = blockIdx.y, b = blockIdx.z;
    const int i0 = iblk * 64;
    const int lane = tid & 63, ct = tid >> 6, l15 = lane & 15, l4 = lane >> 4;

    if (tid < 64) {
        float l = 0.f;
#pragma unroll
        for (int js = 0; js < JSPLIT; ++js)
            l += PL[(size_t)(js * Bb + b) * Nn + i0 + tid];
        sLinv[tid] = 1.0f / l;
    }

    float o[4][4];
#pragma unroll
    for (int it = 0; it < 4; ++it) {
        o[it][0] = o[it][1] = o[it][2] = o[it][3] = 0.f;
#pragma unroll
        for (int js = 0; js < JSPLIT; ++js) {
            size_t base = (size_t)((js * Bb + b) * (Nn / 64) + iblk) * 16384;
            uint2 v = *(const uint2*)&PO[base + (size_t)((((wq * 4 + it) * 4 + ct) * 64 + lane)) * 4];
            o[it][0] += blo(v.x); o[it][1] += bhi(v.x);
            o[it][2] += blo(v.y); o[it][3] += bhi(v.y);
        }
    }

    // transpose into [c_local][i]
    const int cl = ct * 16 + l15;
#pragma unroll
    for (int it = 0; it < 4; ++it) {
        float4 t4 = { o[it][0], o[it][1], o[it][2], o[it][3] };
        *(float4*)&oT[cl * 68 + it * 16 + l4 * 4] = t4;
    }
    __syncthreads();

    const float g = gamma[0];
    const int c_l = tid >> 2, icol = (tid & 3) * 16;
    const int cg = wq * 64 + c_l;
    const size_t gb = (size_t)(b * Cc + cg) * Nn + i0 + icol;
#pragma unroll
    for (int k4 = 0; k4 < 4; ++k4) {
        float4 ov = *(const float4*)&oT[c_l * 68 + icol + k4 * 4];
        float4 li = *(const float4*)&sLinv[icol + k4 * 4];
        float4 xv = *(const float4*)&x[gb + k4 * 4];
        float4 res;
        res.x = fmaf(g, ov.x * li.x, xv.x);
        res.y = fmaf(g, ov.y * li.y, xv.y);
        res.z = fmaf(g, ov.z * li.z, xv.z);
        res.w = fmaf(g, ov.w * li.w, xv.w);
        *(float4*)&out[gb + k4 * 4] = res;
    }
}

// ---------------------------------------------------------------------------
extern "C" void kernel_launch(void* const* d_in, const int* in_sizes, int n_in,
                              void* d_out, int out_size, void* d_ws, size_t ws_size,
                              hipStream_t stream)
{
    const float* x    = (const float*)d_in[0];
    const float* wq   = (const float*)d_in[1];
    const float* wk   = (const float*)d_in[2];
    const float* wv   = (const float*)d_in[3];
    const float* bn1s = (const float*)d_in[4];
    const float* bn1b = (const float*)d_in[5];
    const float* bn1m = (const float*)d_in[6];
    const float* bn1v = (const float*)d_in[7];
    const float* bn2s = (const float*)d_in[8];
    const float* bn2b = (const float*)d_in[9];
    const float* bn2m = (const float*)d_in[10];
    const float* bn2v = (const float*)d_in[11];
    const float* bn3s = (const float*)d_in[12];
    const float* bn3b = (const float*)d_in[13];
    const float* bn3m = (const float*)d_in[14];
    const float* bn3v = (const float*)d_in[15];
    const float* gmm  = (const float*)d_in[16];
    float* out = (float*)d_out;

    // workspace layout (bytes):
    // [Qt 1M][Kt 1M][Vb 8M][PO 16.8M @ +10M][PL 128K @ +43.5M][Wf 160K]
    char* ws = (char*)d_ws;
    __bf16* Qt  = (__bf16*)(ws);
    __bf16* Kt  = (__bf16*)(ws + (1u << 20));
    __bf16* Vb  = (__bf16*)(ws + (2u << 20));
    char*   big = ws + (10u << 20);
    __bf16* PO  = (__bf16*)big;
    float*  PL  = (float*)(big + 33554432);
    __bf16* Wf  = (__bf16*)(big + 33554432 + 262144);

    prep_w<<<dim3(20), 256, 0, stream>>>(wq, wk, wv, Wf);

    qkv_kernel<<<dim3(Nn / 128, 3, Bb), 256, 0, stream>>>(
        x, Wf,
        bn1s, bn1b, bn1m, bn1v,
        bn2s, bn2b, bn2m, bn2v,
        bn3s, bn3b, bn3m, bn3v,
        Qt, Kt, Vb);

    attn_kernel<<<dim3(Nn / 64, JSPLIT, Bb), 512, 0, stream>>>(Qt, Kt, Vb, PO, PL);

    reduce_kernel<<<dim3(Nn / 64, 4, Bb), 256, 0, stream>>>(PO, PL, x, gmm, out);
}